// Round 3
// baseline (591.937 us; speedup 1.0000x reference)
//
#include <hip/hip_runtime.h>

typedef float  f32x4 __attribute__((ext_vector_type(4)));
typedef short  s16x8 __attribute__((ext_vector_type(8)));
typedef unsigned short u16x4 __attribute__((ext_vector_type(4)));

#define MFMA16(a,b,c) __builtin_amdgcn_mfma_f32_16x16x32_bf16(a,b,c,0,0,0)

// sizes: B=128, S=20, T=19, E=H=512, G=2048, V=10000 (padded 10112)
#define PRED_ELEMS 24320000ull
#define NBLK_CHAIN 32

__device__ __forceinline__ unsigned short f2bf(float f){
  unsigned u = __builtin_bit_cast(unsigned, f);
  u += 0x7fffu + ((u >> 16) & 1u);
  return (unsigned short)(u >> 16);
}
__device__ __forceinline__ float sigf(float x){ return 1.0f/(1.0f + __expf(-x)); }
__device__ __forceinline__ float tanh_(float x){
  x = fminf(15.0f, fmaxf(-15.0f, x));
  float e = __expf(2.0f*x);
  return (e - 1.0f) / (e + 1.0f);
}
__device__ __forceinline__ s16x8 ld8(const unsigned short* p){
  return *reinterpret_cast<const s16x8*>(p);
}

// ---------------- K0: stable descending sort by length, tail outputs ----------------
__global__ void k0_sort(const int* __restrict__ length, const int* __restrict__ captions,
                        float* __restrict__ out, int* __restrict__ sortp,
                        int* __restrict__ nactp)
{
  __shared__ int sl[128], sdl[128], ssi[128];
  int tid = threadIdx.x;
  if (tid < 128) sl[tid] = length[tid];
  __syncthreads();
  if (tid < 128){
    int l = sl[tid];
    int rank = 0;
    for (int j = 0; j < 128; ++j){
      int lj = sl[j];
      rank += (lj > l) || (lj == l && j < tid);
    }
    sortp[rank] = tid;
    ssi[rank] = tid;   sdl[rank] = l - 1;
  }
  __syncthreads();
  if (tid < 20){
    int c = 0;
    for (int r = 0; r < 128; ++r) c += (sdl[r] >= tid);
    nactp[tid] = c;
  }
  if (tid < 128){
    const size_t P = PRED_ELEMS;
    int si = ssi[tid];
    for (int t = 0; t < 20; ++t) out[P + tid*20 + t] = (float)captions[si*20 + t];
    out[P + 2560 + tid] = (float)sdl[tid];
    out[P + 2688 + tid] = (float)si;
  }
}

// ---------------- K1: bf16 conversion / gather / zero-init (4-elem units) ----------------
__device__ __forceinline__ void cvt4(unsigned short* dst, const float* src, int u){
  f32x4 v = *reinterpret_cast<const f32x4*>(src + (size_t)u*4);
  u16x4 o;
  o[0]=f2bf(v[0]); o[1]=f2bf(v[1]); o[2]=f2bf(v[2]); o[3]=f2bf(v[3]);
  *reinterpret_cast<u16x4*>(dst + (size_t)u*4) = o;
}

__global__ void k1_convert(const float* __restrict__ images, const int* __restrict__ captions,
    const float* __restrict__ emb, const float* __restrict__ wih, const float* __restrict__ whh,
    const float* __restrict__ bih, const float* __restrict__ bhh, const float* __restrict__ fcw,
    const int* __restrict__ sortp,
    unsigned short* __restrict__ wihb, unsigned short* __restrict__ whhb,
    unsigned short* __restrict__ fcwb, float* __restrict__ biasp,
    unsigned short* __restrict__ xseq, unsigned short* __restrict__ hseq,
    float* __restrict__ cbuf, unsigned int* __restrict__ barcnt)
{
  if (blockIdx.x == 0 && threadIdx.x == 0) *barcnt = 0u;
  const int U0 = 262144;      // W_ih  2048*512/4
  const int U1 = 262144;      // W_hh
  const int U2 = 1294336;     // fc_w padded 10112*512/4
  const int U3 = 512;         // bias 2048/4
  const int U4 = 327680;      // xseq 20*128*512/4
  const int U5 = 16384;       // hseq slot 0 (zero h_init) 128*512/4
  const int U6 = 16384;       // cbuf 128*512/4
  const int total = U0+U1+U2+U3+U4+U5+U6;
  for (int i = blockIdx.x*blockDim.x + threadIdx.x; i < total; i += gridDim.x*blockDim.x){
    int j = i;
    if (j < U0){ cvt4(wihb, wih, j); continue; }
    j -= U0;
    if (j < U1){ cvt4(whhb, whh, j); continue; }
    j -= U1;
    if (j < U2){
      int row = j >> 7;               // (j*4)/512
      if (row < 10000) cvt4(fcwb, fcw, j);
      else { u16x4 z = {0,0,0,0}; *reinterpret_cast<u16x4*>(fcwb + (size_t)j*4) = z; }
      continue;
    }
    j -= U2;
    if (j < U3){
      int e0 = j*4;
      for (int e = 0; e < 4; ++e) biasp[e0+e] = bih[e0+e] + bhh[e0+e];
      continue;
    }
    j -= U3;
    if (j < U4){
      int elem = j*4;
      int s = elem >> 16;             // /65536
      int rem = elem & 65535;
      int r = rem >> 9;
      int k = rem & 511;
      const float* src;
      if (s == 0) src = images + (size_t)sortp[r]*512 + k;
      else {
        int cap = captions[sortp[r]*20 + (s-1)];
        src = emb + (size_t)cap*512 + k;
      }
      f32x4 v = *reinterpret_cast<const f32x4*>(src);
      u16x4 o;
      o[0]=f2bf(v[0]); o[1]=f2bf(v[1]); o[2]=f2bf(v[2]); o[3]=f2bf(v[3]);
      *reinterpret_cast<u16x4*>(xseq + (size_t)j*4) = o;
      continue;
    }
    j -= U4;
    if (j < U5){ u16x4 z = {0,0,0,0}; *reinterpret_cast<u16x4*>(hseq + (size_t)j*4) = z; continue; }
    j -= U5;
    { f32x4 z = {0.f,0.f,0.f,0.f}; *reinterpret_cast<f32x4*>(cbuf + (size_t)j*4) = z; }
  }
}

// ---------------- K2: gx[s][r][g] = x_s @ W_ih^T + bias (all 20 steps batched) ----------------
// grid (16, 20): 128 gate-cols x 128 rows per block; 4 waves 2x2, each 64x64
__global__ __launch_bounds__(256) void k2_gx(
    const unsigned short* __restrict__ xseq, const unsigned short* __restrict__ wihb,
    const float* __restrict__ biasp, float* __restrict__ gx)
{
  const int lane = threadIdx.x & 63;
  const int wv   = threadIdx.x >> 6;
  const int wr   = wv >> 1, wc = wv & 1;
  const int fr   = lane & 15;
  const int fk   = (lane >> 4) * 8;
  const int s    = blockIdx.y;
  const int g0   = blockIdx.x * 128;
  const unsigned short* A = xseq + (size_t)s*65536;

  f32x4 acc[4][4];
  for (int i = 0; i < 4; ++i)
    for (int j = 0; j < 4; ++j)
      acc[i][j] = (f32x4){0.f,0.f,0.f,0.f};

  #pragma unroll 4
  for (int k0 = 0; k0 < 512; k0 += 32){
    s16x8 a[4], b[4];
    for (int i = 0; i < 4; ++i)
      a[i] = ld8(A + (wr*64 + i*16 + fr)*512 + k0 + fk);
    for (int j = 0; j < 4; ++j)
      b[j] = ld8(wihb + (size_t)(g0 + wc*64 + j*16 + fr)*512 + k0 + fk);
    for (int i = 0; i < 4; ++i)
      for (int j = 0; j < 4; ++j)
        acc[i][j] = MFMA16(a[i], b[j], acc[i][j]);
  }

  const int rr = (lane >> 4) * 4;
  for (int j = 0; j < 4; ++j){
    int g = g0 + wc*64 + j*16 + fr;
    float bb = biasp[g];
    for (int i = 0; i < 4; ++i)
      for (int p = 0; p < 4; ++p){
        int r = wr*64 + i*16 + rr + p;
        gx[((size_t)s*128 + r)*2048 + g] = acc[i][j][p] + bb;
      }
  }
}

// ---------------- K3: persistent LSTM chain, 20 steps, device-scope barrier ----------------
// 32 blocks x 512 threads. Block (rb, cb): rows rb*32..+31, j-cols cb*64..+63.
// Wave w: gate q = w&3, row-half rh = w>>2.
__global__ __launch_bounds__(512) void lstm_chain(
    const float* __restrict__ gx, const unsigned short* __restrict__ whh,
    unsigned short* __restrict__ hseq, float* __restrict__ cbuf,
    const int* __restrict__ nact, unsigned int* __restrict__ barcnt)
{
  const int tid  = threadIdx.x;
  const int lane = tid & 63;
  const int w    = tid >> 6;
  const int q    = w & 3;
  const int rh   = w >> 2;
  const int fr   = lane & 15;
  const int fk   = (lane >> 4) * 8;
  const int rb   = blockIdx.x >> 3;
  const int cb   = blockIdx.x & 7;
  const int row0 = rb*32 + rh*16;
  const int col0 = cb*64;
  __shared__ float lg[4][32][65];

  for (int s = 0; s < 20; ++s){
    if (rb*32 < nact[s]){
      const unsigned short* hp = hseq + (size_t)s*65536;       // h_{s-1}
      unsigned short*       hc = hseq + (size_t)(s+1)*65536;   // h_s

      f32x4 acc[4];
      for (int nt = 0; nt < 4; ++nt) acc[nt] = (f32x4){0.f,0.f,0.f,0.f};

      const int g0 = q*512 + col0 + fr;
      #pragma unroll 4
      for (int k0 = 0; k0 < 512; k0 += 32){
        s16x8 a0 = ld8(hp + (row0 + fr)*512 + k0 + fk);
        s16x8 b0 = ld8(whh + (size_t)(g0     )*512 + k0 + fk);
        s16x8 b1 = ld8(whh + (size_t)(g0 + 16)*512 + k0 + fk);
        s16x8 b2 = ld8(whh + (size_t)(g0 + 32)*512 + k0 + fk);
        s16x8 b3 = ld8(whh + (size_t)(g0 + 48)*512 + k0 + fk);
        acc[0] = MFMA16(a0, b0, acc[0]);
        acc[1] = MFMA16(a0, b1, acc[1]);
        acc[2] = MFMA16(a0, b2, acc[2]);
        acc[3] = MFMA16(a0, b3, acc[3]);
      }

      const int rr = (lane >> 4) * 4;
      for (int nt = 0; nt < 4; ++nt)
        for (int p = 0; p < 4; ++p)
          lg[q][rh*16 + rr + p][nt*16 + fr] = acc[nt][p];
      __syncthreads();

      // cell update: 32 rows x 64 cols = 2048 elems, 512 threads x 4
      int r  = tid >> 4;                // 0..31
      int c4 = (tid & 15) * 4;
      int row = rb*32 + r;
      const float* gxr = gx + ((size_t)s*128 + row)*2048;
      for (int jj = 0; jj < 4; ++jj){
        int c = c4 + jj, gj = col0 + c;
        float iv = lg[0][r][c] + gxr[       gj];
        float fv = lg[1][r][c] + gxr[ 512 + gj];
        float gv = lg[2][r][c] + gxr[1024 + gj];
        float ov = lg[3][r][c] + gxr[1536 + gj];
        int idx = row*512 + gj;
        float cn = sigf(fv)*cbuf[idx] + sigf(iv)*tanh_(gv);
        cbuf[idx] = cn;
        hc[idx] = f2bf(sigf(ov)*tanh_(cn));
      }
    }
    // device-scope barrier (generation counter; all blocks participate)
    __syncthreads();
    if (s < 19){
      if (tid == 0){
        __threadfence();
        __hip_atomic_fetch_add(barcnt, 1u, __ATOMIC_RELEASE, __HIP_MEMORY_SCOPE_AGENT);
        unsigned tgt = (unsigned)(s + 1) * NBLK_CHAIN;
        while (__hip_atomic_load(barcnt, __ATOMIC_ACQUIRE, __HIP_MEMORY_SCOPE_AGENT) < tgt) {}
        __threadfence();
      }
      __syncthreads();
    }
  }
}

// ---------------- batched FC with XCD-affine panel mapping ----------------
// 1520 blocks: xcd = b&7, slot = b>>3; panel p = xcd + 8*(slot/19), t = slot%19.
// Consecutive slots on one XCD share panel p -> fc_w panel fetched once per XCD.
__global__ __launch_bounds__(256) void fc_kernel(
    const unsigned short* __restrict__ hseq, const unsigned short* __restrict__ fcwb,
    const float* __restrict__ fcb, const int* __restrict__ nact,
    float* __restrict__ out)
{
  const int b    = blockIdx.x;
  const int xcd  = b & 7;
  const int slot = b >> 3;
  const int p    = xcd + 8 * (slot / 19);
  const int t    = slot % 19;
  if (p >= 79) return;

  const int lane = threadIdx.x & 63;
  const int wv   = threadIdx.x >> 6;
  const int wr   = wv >> 1, wc = wv & 1;
  const int fr   = lane & 15;
  const int fk   = (lane >> 4) * 8;

  const int v0  = p * 128;
  const int n_t = nact[t + 1];

  const unsigned short* A = hseq + (size_t)(t + 2)*65536;  // h_{t+1}, 128x512

  f32x4 acc[4][4];
  for (int i = 0; i < 4; ++i)
    for (int j = 0; j < 4; ++j)
      acc[i][j] = (f32x4){0.f,0.f,0.f,0.f};

  if (wr*64 < n_t){
    #pragma unroll 4
    for (int k0 = 0; k0 < 512; k0 += 32){
      s16x8 a[4], b8[4];
      for (int i = 0; i < 4; ++i)
        a[i] = ld8(A + (wr*64 + i*16 + fr)*512 + k0 + fk);
      for (int j = 0; j < 4; ++j)
        b8[j] = ld8(fcwb + (size_t)(v0 + wc*64 + j*16 + fr)*512 + k0 + fk);
      for (int i = 0; i < 4; ++i)
        for (int j = 0; j < 4; ++j)
          acc[i][j] = MFMA16(a[i], b8[j], acc[i][j]);
    }
  }

  const int rr = (lane >> 4) * 4;
  for (int j = 0; j < 4; ++j){
    int v = v0 + wc*64 + j*16 + fr;
    if (v >= 10000) continue;
    float bb = fcb[v];
    for (int i = 0; i < 4; ++i){
      for (int pp = 0; pp < 4; ++pp){
        int r = wr*64 + i*16 + rr + pp;
        out[(size_t)(r*19 + t)*10000 + v] = (r < n_t) ? (acc[i][j][pp] + bb) : 0.0f;
      }
    }
  }
}

extern "C" void kernel_launch(void* const* d_in, const int* in_sizes, int n_in,
                              void* d_out, int out_size, void* d_ws, size_t ws_size,
                              hipStream_t stream) {
  const float* images   = (const float*)d_in[0];
  const int*   captions = (const int*)  d_in[1];
  const int*   length   = (const int*)  d_in[2];
  const float* emb      = (const float*)d_in[3];
  const float* W_ih     = (const float*)d_in[4];
  const float* W_hh     = (const float*)d_in[5];
  const float* b_ih     = (const float*)d_in[6];
  const float* b_hh     = (const float*)d_in[7];
  const float* fc_w     = (const float*)d_in[8];
  const float* fc_b     = (const float*)d_in[9];
  float* out = (float*)d_out;
  char*  ws  = (char*)d_ws;

  int*            sortp  = (int*)           (ws + 0);
  int*            nactp  = (int*)           (ws + 2048);
  float*          biasp  = (float*)         (ws + 4096);
  unsigned int*   barcnt = (unsigned int*)  (ws + 12288);
  float*          cbuf   = (float*)         (ws + 16384);
  unsigned short* hseq   = (unsigned short*)(ws + 278528);    // 21 slots x 128x512 bf16
  unsigned short* xseq   = (unsigned short*)(ws + 3031040);   // 20 slots
  unsigned short* wihb   = (unsigned short*)(ws + 5652480);
  unsigned short* whhb   = (unsigned short*)(ws + 7749632);
  unsigned short* fcwb   = (unsigned short*)(ws + 9846784);   // 10112x512 bf16
  float*          gx     = (float*)         (ws + 20201472);  // 20x128x2048 f32, ends ~41.2 MB

  k0_sort<<<1, 128, 0, stream>>>(length, captions, out, sortp, nactp);
  k1_convert<<<4096, 256, 0, stream>>>(images, captions, emb, W_ih, W_hh, b_ih, b_hh,
                                       fc_w, sortp, wihb, whhb, fcwb, biasp, xseq, hseq,
                                       cbuf, barcnt);
  k2_gx<<<dim3(16, 20), 256, 0, stream>>>(xseq, wihb, biasp, gx);
  lstm_chain<<<NBLK_CHAIN, 512, 0, stream>>>(gx, whhb, hseq, cbuf, nactp, barcnt);
  fc_kernel<<<1520, 256, 0, stream>>>(hseq, fcwb, fc_b, nactp, out);
}

// Round 4
// 360.323 us; speedup vs baseline: 1.6428x; 1.6428x over previous
//
#include <hip/hip_runtime.h>

typedef float  f32x4 __attribute__((ext_vector_type(4)));
typedef short  s16x8 __attribute__((ext_vector_type(8)));
typedef unsigned short u16x4 __attribute__((ext_vector_type(4)));

#define MFMA16(a,b,c) __builtin_amdgcn_mfma_f32_16x16x32_bf16(a,b,c,0,0,0)

// sizes: B=128, S=20, T=19, E=H=512, G=2048, V=10000 (padded 10112)
#define PRED_ELEMS 24320000ull

__device__ __forceinline__ unsigned short f2bf(float f){
  unsigned u = __builtin_bit_cast(unsigned, f);
  u += 0x7fffu + ((u >> 16) & 1u);
  return (unsigned short)(u >> 16);
}
__device__ __forceinline__ float sigf(float x){ return 1.0f/(1.0f + __expf(-x)); }
__device__ __forceinline__ float tanh_(float x){
  x = fminf(15.0f, fmaxf(-15.0f, x));
  float e = __expf(2.0f*x);
  return (e - 1.0f) / (e + 1.0f);
}
__device__ __forceinline__ s16x8 ld8(const unsigned short* p){
  return *reinterpret_cast<const s16x8*>(p);
}

// ---------------- K0: stable descending sort by length, tail outputs, cnt init ----------------
__global__ void k0_sort(const int* __restrict__ length, const int* __restrict__ captions,
                        float* __restrict__ out, int* __restrict__ sortp,
                        int* __restrict__ nactp, unsigned int* __restrict__ cnt)
{
  __shared__ int sl[128], sdl[128], ssi[128];
  int tid = threadIdx.x;
  if (tid < 8) cnt[tid] = 0u;
  if (tid < 128) sl[tid] = length[tid];
  __syncthreads();
  if (tid < 128){
    int l = sl[tid];
    int rank = 0;
    for (int j = 0; j < 128; ++j){
      int lj = sl[j];
      rank += (lj > l) || (lj == l && j < tid);
    }
    sortp[rank] = tid;
    ssi[rank] = tid;   sdl[rank] = l - 1;
  }
  __syncthreads();
  if (tid < 20){
    int c = 0;
    for (int r = 0; r < 128; ++r) c += (sdl[r] >= tid);
    nactp[tid] = c;
  }
  if (tid < 128){
    const size_t P = PRED_ELEMS;
    int si = ssi[tid];
    for (int t = 0; t < 20; ++t) out[P + tid*20 + t] = (float)captions[si*20 + t];
    out[P + 2560 + tid] = (float)sdl[tid];
    out[P + 2688 + tid] = (float)si;
  }
}

// ---------------- K1: bf16 conversion / gather / zero-init (4-elem units) ----------------
__device__ __forceinline__ void cvt4(unsigned short* dst, const float* src, int u){
  f32x4 v = *reinterpret_cast<const f32x4*>(src + (size_t)u*4);
  u16x4 o;
  o[0]=f2bf(v[0]); o[1]=f2bf(v[1]); o[2]=f2bf(v[2]); o[3]=f2bf(v[3]);
  *reinterpret_cast<u16x4*>(dst + (size_t)u*4) = o;
}

__global__ void k1_convert(const float* __restrict__ images, const int* __restrict__ captions,
    const float* __restrict__ emb, const float* __restrict__ wih, const float* __restrict__ whh,
    const float* __restrict__ bih, const float* __restrict__ bhh, const float* __restrict__ fcw,
    const int* __restrict__ sortp,
    unsigned short* __restrict__ wihb, unsigned short* __restrict__ whhb,
    unsigned short* __restrict__ fcwb, float* __restrict__ biasp,
    unsigned short* __restrict__ xseq, unsigned short* __restrict__ hseq)
{
  const int U0 = 262144;      // W_ih  2048*512/4
  const int U1 = 262144;      // W_hh
  const int U2 = 1294336;     // fc_w padded 10112*512/4
  const int U3 = 512;         // bias 2048/4
  const int U4 = 327680;      // xseq 20*128*512/4
  const int U5 = 16384;       // hseq slot 0 (zero h_init) 128*512/4
  const int total = U0+U1+U2+U3+U4+U5;
  for (int i = blockIdx.x*blockDim.x + threadIdx.x; i < total; i += gridDim.x*blockDim.x){
    int j = i;
    if (j < U0){ cvt4(wihb, wih, j); continue; }
    j -= U0;
    if (j < U1){ cvt4(whhb, whh, j); continue; }
    j -= U1;
    if (j < U2){
      int row = j >> 7;               // (j*4)/512
      if (row < 10000) cvt4(fcwb, fcw, j);
      else { u16x4 z = {0,0,0,0}; *reinterpret_cast<u16x4*>(fcwb + (size_t)j*4) = z; }
      continue;
    }
    j -= U2;
    if (j < U3){
      int e0 = j*4;
      for (int e = 0; e < 4; ++e) biasp[e0+e] = bih[e0+e] + bhh[e0+e];
      continue;
    }
    j -= U3;
    if (j < U4){
      int elem = j*4;
      int s = elem >> 16;             // /65536
      int rem = elem & 65535;
      int r = rem >> 9;
      int k = rem & 511;
      const float* src;
      if (s == 0) src = images + (size_t)sortp[r]*512 + k;
      else {
        int cap = captions[sortp[r]*20 + (s-1)];
        src = emb + (size_t)cap*512 + k;
      }
      f32x4 v = *reinterpret_cast<const f32x4*>(src);
      u16x4 o;
      o[0]=f2bf(v[0]); o[1]=f2bf(v[1]); o[2]=f2bf(v[2]); o[3]=f2bf(v[3]);
      *reinterpret_cast<u16x4*>(xseq + (size_t)j*4) = o;
      continue;
    }
    j -= U4;
    { u16x4 z = {0,0,0,0}; *reinterpret_cast<u16x4*>(hseq + (size_t)j*4) = z; }
  }
}

// ---------------- K2: gx[s][r][g] = x_s @ W_ih^T + bias (all 20 steps batched) ----------------
__global__ __launch_bounds__(256) void k2_gx(
    const unsigned short* __restrict__ xseq, const unsigned short* __restrict__ wihb,
    const float* __restrict__ biasp, float* __restrict__ gx)
{
  const int lane = threadIdx.x & 63;
  const int wv   = threadIdx.x >> 6;
  const int wr   = wv >> 1, wc = wv & 1;
  const int fr   = lane & 15;
  const int fk   = (lane >> 4) * 8;
  const int s    = blockIdx.y;
  const int g0   = blockIdx.x * 128;
  const unsigned short* A = xseq + (size_t)s*65536;

  f32x4 acc[4][4];
  for (int i = 0; i < 4; ++i)
    for (int j = 0; j < 4; ++j)
      acc[i][j] = (f32x4){0.f,0.f,0.f,0.f};

  #pragma unroll 4
  for (int k0 = 0; k0 < 512; k0 += 32){
    s16x8 a[4], b[4];
    for (int i = 0; i < 4; ++i)
      a[i] = ld8(A + (wr*64 + i*16 + fr)*512 + k0 + fk);
    for (int j = 0; j < 4; ++j)
      b[j] = ld8(wihb + (size_t)(g0 + wc*64 + j*16 + fr)*512 + k0 + fk);
    for (int i = 0; i < 4; ++i)
      for (int j = 0; j < 4; ++j)
        acc[i][j] = MFMA16(a[i], b[j], acc[i][j]);
  }

  const int rr = (lane >> 4) * 4;
  for (int j = 0; j < 4; ++j){
    int g = g0 + wc*64 + j*16 + fr;
    float bb = biasp[g];
    for (int i = 0; i < 4; ++i)
      for (int p = 0; p < 4; ++p){
        int r = wr*64 + i*16 + rr + p;
        gx[((size_t)s*128 + r)*2048 + g] = acc[i][j][p] + bb;
      }
  }
}

// ---------------- K3: persistent LSTM chain, W_hh slice in LDS, c in registers ----------------
// 64 blocks (rb 0..3 x cb 0..15), 512 threads. Block computes rows rb*32..+31,
// h-cols cb*32..+31 (gate cols {q*512+cb*32+j}). Barrier: per-rb-group counter,
// relaxed spin + s_sleep, one release-add / acquire-load per block per step.
__global__ __launch_bounds__(512) void lstm_chain(
    const float* __restrict__ gx, const unsigned short* __restrict__ whh,
    unsigned short* __restrict__ hseq, const int* __restrict__ nact,
    unsigned int* __restrict__ cnt)
{
  const int tid  = threadIdx.x;
  const int lane = tid & 63;
  const int w    = tid >> 6;
  const int rh   = w >> 2;            // row half (16 rows)
  const int qc   = w & 3;             // gate (local gatecol 32-slice)
  const int fr   = lane & 15;
  const int fk   = (lane >> 4) * 8;
  const int rb   = blockIdx.x >> 4;   // 0..3
  const int cb   = blockIdx.x & 15;   // 0..15
  unsigned int* mycnt = cnt + rb;

  __shared__ unsigned short Wl[128*520];   // 133 KB, padded stride 520
  __shared__ float lg[32][132];            // 16.9 KB

  // preload W_hh slice: local row lr = q*32+j  <->  global gatecol q*512 + cb*32 + j
  for (int idx = tid; idx < 128*64; idx += 512){
    int lr = idx >> 6, kc = (idx & 63) * 8;
    int q = lr >> 5, jj = lr & 31;
    s16x8 v = ld8(whh + (size_t)(q*512 + cb*32 + jj)*512 + kc);
    *reinterpret_cast<s16x8*>(&Wl[lr*520 + kc]) = v;
  }
  __syncthreads();

  // pointwise ownership: row prow, local h-col pair pj
  const int prow = rb*32 + (tid >> 4);
  const int pj   = (tid & 15) * 2;
  float creg0 = 0.f, creg1 = 0.f;

  for (int s = 0; s < 20; ++s){
    if (rb*32 >= nact[s]) break;
    const unsigned short* hp = hseq + (size_t)s*65536;
    unsigned short*       hc = hseq + (size_t)(s+1)*65536;

    // GEMM: rows rh*16..+15, local gatecols qc*32..+31
    f32x4 acc0 = (f32x4){0.f,0.f,0.f,0.f};
    f32x4 acc1 = (f32x4){0.f,0.f,0.f,0.f};
    const int arow = rb*32 + rh*16 + fr;
    #pragma unroll 4
    for (int k0 = 0; k0 < 512; k0 += 32){
      s16x8 a  = ld8(hp + arow*512 + k0 + fk);
      s16x8 b0 = *reinterpret_cast<const s16x8*>(&Wl[(qc*32      + fr)*520 + k0 + fk]);
      s16x8 b1 = *reinterpret_cast<const s16x8*>(&Wl[(qc*32 + 16 + fr)*520 + k0 + fk]);
      acc0 = MFMA16(a, b0, acc0);
      acc1 = MFMA16(a, b1, acc1);
    }
    const int rr = (lane >> 4) * 4;
    for (int p = 0; p < 4; ++p){
      lg[rh*16 + rr + p][qc*32      + fr] = acc0[p];
      lg[rh*16 + rr + p][qc*32 + 16 + fr] = acc1[p];
    }
    __syncthreads();

    // pointwise: i,f,g,o at local cols {pj, 32+pj, 64+pj, 96+pj}
    {
      const float* gxr = gx + ((size_t)s*128 + prow)*2048 + cb*32;
      const int lr = tid >> 4;
      float iv0 = lg[lr][pj]      + gxr[pj];
      float fv0 = lg[lr][32 + pj] + gxr[512 + pj];
      float gv0 = lg[lr][64 + pj] + gxr[1024 + pj];
      float ov0 = lg[lr][96 + pj] + gxr[1536 + pj];
      float iv1 = lg[lr][pj + 1]      + gxr[pj + 1];
      float fv1 = lg[lr][33 + pj] + gxr[513 + pj];
      float gv1 = lg[lr][65 + pj] + gxr[1025 + pj];
      float ov1 = lg[lr][97 + pj] + gxr[1537 + pj];
      creg0 = sigf(fv0)*creg0 + sigf(iv0)*tanh_(gv0);
      creg1 = sigf(fv1)*creg1 + sigf(iv1)*tanh_(gv1);
      float h0 = sigf(ov0)*tanh_(creg0);
      float h1 = sigf(ov1)*tanh_(creg1);
      unsigned hword = (unsigned)f2bf(h0) | ((unsigned)f2bf(h1) << 16);
      *reinterpret_cast<unsigned*>(hc + (size_t)prow*512 + cb*32 + pj) = hword;
    }
    __syncthreads();   // drain all waves' stores, protect lg

    if (s < 19 && nact[s+1] > rb*32){
      if (tid == 0){
        __hip_atomic_fetch_add(mycnt, 1u, __ATOMIC_RELEASE, __HIP_MEMORY_SCOPE_AGENT);
        unsigned tgt = (unsigned)(s + 1) * 16u;
        long guard = 0;
        while (__hip_atomic_load(mycnt, __ATOMIC_RELAXED, __HIP_MEMORY_SCOPE_AGENT) < tgt
               && ++guard < (1L << 30))
          __builtin_amdgcn_s_sleep(1);
        (void)__hip_atomic_load(mycnt, __ATOMIC_ACQUIRE, __HIP_MEMORY_SCOPE_AGENT);
      }
      __syncthreads();
    }
  }
}

// ---------------- K4: batched FC, fc_w panel in LDS, t-loop ----------------
// 316 blocks = 79 panels x 4 t-quarters; 512 threads, 8 waves (wr 2 x wc 4).
__global__ __launch_bounds__(512) void fc_kernel(
    const unsigned short* __restrict__ hseq, const unsigned short* __restrict__ fcwb,
    const float* __restrict__ fcb, const int* __restrict__ nact,
    float* __restrict__ out)
{
  const int b    = blockIdx.x;
  const int p    = b >> 2;
  const int qu   = b & 3;
  const int v0   = p * 128;
  const int tid  = threadIdx.x;
  const int lane = tid & 63;
  const int w    = tid >> 6;
  const int wr   = w >> 2;            // 0..1: 64-row half
  const int wc   = w & 3;             // 0..3: 32-col slice
  const int fr   = lane & 15;
  const int fk   = (lane >> 4) * 8;

  __shared__ unsigned short Bl[128*520];
  for (int idx = tid; idx < 128*64; idx += 512){
    int lr = idx >> 6, kc = (idx & 63) * 8;
    s16x8 v = ld8(fcwb + (size_t)(v0 + lr)*512 + kc);
    *reinterpret_cast<s16x8*>(&Bl[lr*520 + kc]) = v;
  }
  __syncthreads();

  float bb[2];
  for (int j = 0; j < 2; ++j){
    int v = v0 + wc*32 + j*16 + fr;
    bb[j] = (v < 10000) ? fcb[v] : 0.f;
  }

  const int tcnt = (qu == 3) ? 4 : 5;
  for (int ti = 0; ti < tcnt; ++ti){
    const int t   = qu*5 + ti;
    const int n_t = nact[t + 1];
    const unsigned short* A = hseq + (size_t)(t + 2)*65536;

    f32x4 acc[4][2];
    for (int i = 0; i < 4; ++i){
      acc[i][0] = (f32x4){0.f,0.f,0.f,0.f};
      acc[i][1] = (f32x4){0.f,0.f,0.f,0.f};
    }

    if (wr*64 < n_t){
      #pragma unroll 4
      for (int k0 = 0; k0 < 512; k0 += 32){
        s16x8 a[4], bfr[2];
        for (int i = 0; i < 4; ++i)
          a[i] = ld8(A + (size_t)(wr*64 + i*16 + fr)*512 + k0 + fk);
        for (int j = 0; j < 2; ++j)
          bfr[j] = *reinterpret_cast<const s16x8*>(&Bl[(wc*32 + j*16 + fr)*520 + k0 + fk]);
        for (int i = 0; i < 4; ++i)
          for (int j = 0; j < 2; ++j)
            acc[i][j] = MFMA16(a[i], bfr[j], acc[i][j]);
      }
    }

    const int rr = (lane >> 4) * 4;
    for (int j = 0; j < 2; ++j){
      int v = v0 + wc*32 + j*16 + fr;
      if (v >= 10000) continue;
      for (int i = 0; i < 4; ++i)
        for (int pp = 0; pp < 4; ++pp){
          int r = wr*64 + i*16 + rr + pp;
          out[(size_t)(r*19 + t)*10000 + v] = (r < n_t) ? (acc[i][j][pp] + bb[j]) : 0.0f;
        }
    }
  }
}

extern "C" void kernel_launch(void* const* d_in, const int* in_sizes, int n_in,
                              void* d_out, int out_size, void* d_ws, size_t ws_size,
                              hipStream_t stream) {
  const float* images   = (const float*)d_in[0];
  const int*   captions = (const int*)  d_in[1];
  const int*   length   = (const int*)  d_in[2];
  const float* emb      = (const float*)d_in[3];
  const float* W_ih     = (const float*)d_in[4];
  const float* W_hh     = (const float*)d_in[5];
  const float* b_ih     = (const float*)d_in[6];
  const float* b_hh     = (const float*)d_in[7];
  const float* fc_w     = (const float*)d_in[8];
  const float* fc_b     = (const float*)d_in[9];
  float* out = (float*)d_out;
  char*  ws  = (char*)d_ws;

  int*            sortp  = (int*)           (ws + 0);
  int*            nactp  = (int*)           (ws + 2048);
  float*          biasp  = (float*)         (ws + 4096);
  unsigned int*   cnt    = (unsigned int*)  (ws + 12288);
  unsigned short* hseq   = (unsigned short*)(ws + 278528);    // 21 slots x 128x512 bf16
  unsigned short* xseq   = (unsigned short*)(ws + 3031040);   // 20 slots
  unsigned short* wihb   = (unsigned short*)(ws + 5652480);
  unsigned short* whhb   = (unsigned short*)(ws + 7749632);
  unsigned short* fcwb   = (unsigned short*)(ws + 9846784);   // 10112x512 bf16
  float*          gx     = (float*)         (ws + 20201472);  // 20x128x2048 f32, ends ~41.2 MB

  k0_sort<<<1, 128, 0, stream>>>(length, captions, out, sortp, nactp, cnt);
  k1_convert<<<4096, 256, 0, stream>>>(images, captions, emb, W_ih, W_hh, b_ih, b_hh,
                                       fc_w, sortp, wihb, whhb, fcwb, biasp, xseq, hseq);
  k2_gx<<<dim3(16, 20), 256, 0, stream>>>(xseq, wihb, biasp, gx);
  lstm_chain<<<64, 512, 0, stream>>>(gx, whhb, hseq, nactp, cnt);
  fc_kernel<<<316, 512, 0, stream>>>(hseq, fcwb, fc_b, nactp, out);
}

// Round 5
// 269.290 us; speedup vs baseline: 2.1981x; 1.3380x over previous
//
#include <hip/hip_runtime.h>

typedef float  f32x4 __attribute__((ext_vector_type(4)));
typedef short  s16x8 __attribute__((ext_vector_type(8)));
typedef unsigned short u16x4 __attribute__((ext_vector_type(4)));

#define MFMA16(a,b,c) __builtin_amdgcn_mfma_f32_16x16x32_bf16(a,b,c,0,0,0)

// sizes: B=128, S=20, T=19, E=H=512, G=2048, V=10000 (padded 10112)
#define PRED_ELEMS 24320000ull

__device__ __forceinline__ unsigned short f2bf(float f){
  unsigned u = __builtin_bit_cast(unsigned, f);
  u += 0x7fffu + ((u >> 16) & 1u);
  return (unsigned short)(u >> 16);
}
__device__ __forceinline__ float sigf(float x){ return 1.0f/(1.0f + __expf(-x)); }
__device__ __forceinline__ float tanh_(float x){
  x = fminf(15.0f, fmaxf(-15.0f, x));
  float e = __expf(2.0f*x);
  return (e - 1.0f) / (e + 1.0f);
}
__device__ __forceinline__ s16x8 ld8(const unsigned short* p){
  return *reinterpret_cast<const s16x8*>(p);
}

// ---------------- K0: stable descending sort by length, tail outputs, cnt init ----------------
__global__ void k0_sort(const int* __restrict__ length, const int* __restrict__ captions,
                        float* __restrict__ out, int* __restrict__ sortp,
                        int* __restrict__ nactp, unsigned int* __restrict__ cnt)
{
  __shared__ int sl[128], sdl[128], ssi[128];
  int tid = threadIdx.x;
  if (tid < 8) cnt[tid] = 0u;
  if (tid < 128) sl[tid] = length[tid];
  __syncthreads();
  if (tid < 128){
    int l = sl[tid];
    int rank = 0;
    for (int j = 0; j < 128; ++j){
      int lj = sl[j];
      rank += (lj > l) || (lj == l && j < tid);
    }
    sortp[rank] = tid;
    ssi[rank] = tid;   sdl[rank] = l - 1;
  }
  __syncthreads();
  if (tid < 20){
    int c = 0;
    for (int r = 0; r < 128; ++r) c += (sdl[r] >= tid);
    nactp[tid] = c;
  }
  if (tid < 128){
    const size_t P = PRED_ELEMS;
    int si = ssi[tid];
    for (int t = 0; t < 20; ++t) out[P + tid*20 + t] = (float)captions[si*20 + t];
    out[P + 2560 + tid] = (float)sdl[tid];
    out[P + 2688 + tid] = (float)si;
  }
}

// ---------------- K1: bf16 conversion / gather / zero-init (4-elem units) ----------------
__device__ __forceinline__ void cvt4(unsigned short* dst, const float* src, int u){
  f32x4 v = *reinterpret_cast<const f32x4*>(src + (size_t)u*4);
  u16x4 o;
  o[0]=f2bf(v[0]); o[1]=f2bf(v[1]); o[2]=f2bf(v[2]); o[3]=f2bf(v[3]);
  *reinterpret_cast<u16x4*>(dst + (size_t)u*4) = o;
}

__global__ void k1_convert(const float* __restrict__ images, const int* __restrict__ captions,
    const float* __restrict__ emb, const float* __restrict__ wih, const float* __restrict__ whh,
    const float* __restrict__ bih, const float* __restrict__ bhh, const float* __restrict__ fcw,
    const int* __restrict__ sortp,
    unsigned short* __restrict__ wihb, unsigned short* __restrict__ whhb,
    unsigned short* __restrict__ fcwb, float* __restrict__ biasp,
    unsigned short* __restrict__ xseq, unsigned short* __restrict__ hseq)
{
  const int U0 = 262144;      // W_ih  2048*512/4
  const int U1 = 262144;      // W_hh
  const int U2 = 1294336;     // fc_w padded 10112*512/4
  const int U3 = 512;         // bias 2048/4
  const int U4 = 327680;      // xseq 20*128*512/4
  const int U5 = 16384;       // hseq slot 0 (zero h_init) 128*512/4
  const int total = U0+U1+U2+U3+U4+U5;
  for (int i = blockIdx.x*blockDim.x + threadIdx.x; i < total; i += gridDim.x*blockDim.x){
    int j = i;
    if (j < U0){ cvt4(wihb, wih, j); continue; }
    j -= U0;
    if (j < U1){ cvt4(whhb, whh, j); continue; }
    j -= U1;
    if (j < U2){
      int row = j >> 7;               // (j*4)/512
      if (row < 10000) cvt4(fcwb, fcw, j);
      else { u16x4 z = {0,0,0,0}; *reinterpret_cast<u16x4*>(fcwb + (size_t)j*4) = z; }
      continue;
    }
    j -= U2;
    if (j < U3){
      int e0 = j*4;
      for (int e = 0; e < 4; ++e) biasp[e0+e] = bih[e0+e] + bhh[e0+e];
      continue;
    }
    j -= U3;
    if (j < U4){
      int elem = j*4;
      int s = elem >> 16;             // /65536
      int rem = elem & 65535;
      int r = rem >> 9;
      int k = rem & 511;
      const float* src;
      if (s == 0) src = images + (size_t)sortp[r]*512 + k;
      else {
        int cap = captions[sortp[r]*20 + (s-1)];
        src = emb + (size_t)cap*512 + k;
      }
      f32x4 v = *reinterpret_cast<const f32x4*>(src);
      u16x4 o;
      o[0]=f2bf(v[0]); o[1]=f2bf(v[1]); o[2]=f2bf(v[2]); o[3]=f2bf(v[3]);
      *reinterpret_cast<u16x4*>(xseq + (size_t)j*4) = o;
      continue;
    }
    j -= U4;
    { u16x4 z = {0,0,0,0}; *reinterpret_cast<u16x4*>(hseq + (size_t)j*4) = z; }
  }
}

// ---------------- K2: gx[s][r][g] = x_s @ W_ih^T + bias (all 20 steps batched) ----------------
__global__ __launch_bounds__(256) void k2_gx(
    const unsigned short* __restrict__ xseq, const unsigned short* __restrict__ wihb,
    const float* __restrict__ biasp, float* __restrict__ gx)
{
  const int lane = threadIdx.x & 63;
  const int wv   = threadIdx.x >> 6;
  const int wr   = wv >> 1, wc = wv & 1;
  const int fr   = lane & 15;
  const int fk   = (lane >> 4) * 8;
  const int s    = blockIdx.y;
  const int g0   = blockIdx.x * 128;
  const unsigned short* A = xseq + (size_t)s*65536;

  f32x4 acc[4][4];
  for (int i = 0; i < 4; ++i)
    for (int j = 0; j < 4; ++j)
      acc[i][j] = (f32x4){0.f,0.f,0.f,0.f};

  #pragma unroll 4
  for (int k0 = 0; k0 < 512; k0 += 32){
    s16x8 a[4], b[4];
    for (int i = 0; i < 4; ++i)
      a[i] = ld8(A + (wr*64 + i*16 + fr)*512 + k0 + fk);
    for (int j = 0; j < 4; ++j)
      b[j] = ld8(wihb + (size_t)(g0 + wc*64 + j*16 + fr)*512 + k0 + fk);
    for (int i = 0; i < 4; ++i)
      for (int j = 0; j < 4; ++j)
        acc[i][j] = MFMA16(a[i], b[j], acc[i][j]);
  }

  const int rr = (lane >> 4) * 4;
  for (int j = 0; j < 4; ++j){
    int g = g0 + wc*64 + j*16 + fr;
    float bb = biasp[g];
    for (int i = 0; i < 4; ++i)
      for (int p = 0; p < 4; ++p){
        int r = wr*64 + i*16 + rr + p;
        gx[((size_t)s*128 + r)*2048 + g] = acc[i][j][p] + bb;
      }
  }
}

// ---------------- K3: persistent LSTM chain, W_hh slice in LDS, c in registers ----------------
// 64 blocks (rb 0..3 x cb 0..15), 512 threads. Block: rows rb*32..+31, h-cols cb*32..+31.
// Per step: issue ALL 16 A-frags + gx as one load burst (hide post-inv cold latency),
// then LDS-B MFMA, pointwise, h-store, per-rb-group relaxed barrier.
__global__ __launch_bounds__(512) void lstm_chain(
    const float* __restrict__ gx, const unsigned short* __restrict__ whh,
    unsigned short* __restrict__ hseq, const int* __restrict__ nact,
    unsigned int* __restrict__ cnt)
{
  const int tid  = threadIdx.x;
  const int lane = tid & 63;
  const int w    = tid >> 6;
  const int rh   = w >> 2;            // row half (16 rows)
  const int qc   = w & 3;             // gate (local gatecol 32-slice)
  const int fr   = lane & 15;
  const int fk   = (lane >> 4) * 8;
  const int rb   = blockIdx.x >> 4;   // 0..3
  const int cb   = blockIdx.x & 15;   // 0..15
  unsigned int* mycnt = cnt + rb;

  __shared__ unsigned short Wl[128*520];   // 133 KB
  __shared__ float lg[32][132];            // 16.9 KB

  for (int idx = tid; idx < 128*64; idx += 512){
    int lr = idx >> 6, kc = (idx & 63) * 8;
    int q = lr >> 5, jj = lr & 31;
    s16x8 v = ld8(whh + (size_t)(q*512 + cb*32 + jj)*512 + kc);
    *reinterpret_cast<s16x8*>(&Wl[lr*520 + kc]) = v;
  }
  __syncthreads();

  const int prow = rb*32 + (tid >> 4);
  const int pj   = (tid & 15) * 2;
  const int arow = rb*32 + rh*16 + fr;
  float creg0 = 0.f, creg1 = 0.f;

  for (int s = 0; s < 20; ++s){
    if (rb*32 >= nact[s]) break;
    const unsigned short* hp = hseq + (size_t)s*65536;
    unsigned short*       hc = hseq + (size_t)(s+1)*65536;

    // one burst: 16 independent A-frags + 4 gx float2s
    s16x8 a[16];
    #pragma unroll
    for (int k = 0; k < 16; ++k)
      a[k] = ld8(hp + arow*512 + k*32 + fk);
    const float* gxr = gx + ((size_t)s*128 + prow)*2048 + cb*32 + pj;
    float2 gvi = *reinterpret_cast<const float2*>(gxr);
    float2 gvf = *reinterpret_cast<const float2*>(gxr + 512);
    float2 gvg = *reinterpret_cast<const float2*>(gxr + 1024);
    float2 gvo = *reinterpret_cast<const float2*>(gxr + 1536);

    f32x4 acc0 = (f32x4){0.f,0.f,0.f,0.f};
    f32x4 acc1 = (f32x4){0.f,0.f,0.f,0.f};
    #pragma unroll
    for (int k = 0; k < 16; ++k){
      s16x8 b0 = *reinterpret_cast<const s16x8*>(&Wl[(qc*32      + fr)*520 + k*32 + fk]);
      s16x8 b1 = *reinterpret_cast<const s16x8*>(&Wl[(qc*32 + 16 + fr)*520 + k*32 + fk]);
      acc0 = MFMA16(a[k], b0, acc0);
      acc1 = MFMA16(a[k], b1, acc1);
    }
    const int rr = (lane >> 4) * 4;
    #pragma unroll
    for (int p = 0; p < 4; ++p){
      lg[rh*16 + rr + p][qc*32      + fr] = acc0[p];
      lg[rh*16 + rr + p][qc*32 + 16 + fr] = acc1[p];
    }
    __syncthreads();

    {
      const int lr = tid >> 4;
      float iv0 = lg[lr][pj]      + gvi.x;
      float iv1 = lg[lr][pj + 1]  + gvi.y;
      float fv0 = lg[lr][32 + pj] + gvf.x;
      float fv1 = lg[lr][33 + pj] + gvf.y;
      float gv0 = lg[lr][64 + pj] + gvg.x;
      float gv1 = lg[lr][65 + pj] + gvg.y;
      float ov0 = lg[lr][96 + pj] + gvo.x;
      float ov1 = lg[lr][97 + pj] + gvo.y;
      creg0 = sigf(fv0)*creg0 + sigf(iv0)*tanh_(gv0);
      creg1 = sigf(fv1)*creg1 + sigf(iv1)*tanh_(gv1);
      float h0 = sigf(ov0)*tanh_(creg0);
      float h1 = sigf(ov1)*tanh_(creg1);
      unsigned hword = (unsigned)f2bf(h0) | ((unsigned)f2bf(h1) << 16);
      *reinterpret_cast<unsigned*>(hc + (size_t)prow*512 + cb*32 + pj) = hword;
    }
    __syncthreads();

    if (s < 19 && nact[s+1] > rb*32){
      if (tid == 0){
        __hip_atomic_fetch_add(mycnt, 1u, __ATOMIC_RELEASE, __HIP_MEMORY_SCOPE_AGENT);
        unsigned tgt = (unsigned)(s + 1) * 16u;
        long guard = 0;
        while (__hip_atomic_load(mycnt, __ATOMIC_RELAXED, __HIP_MEMORY_SCOPE_AGENT) < tgt
               && ++guard < (1L << 30))
          __builtin_amdgcn_s_sleep(1);
        (void)__hip_atomic_load(mycnt, __ATOMIC_ACQUIRE, __HIP_MEMORY_SCOPE_AGENT);
      }
      __syncthreads();
    }
  }
}

// ---------------- K4: batched FC, 64-col fc_w panel in LDS (2 blocks/CU), t-loop ----------------
// 640 blocks: x=b&7 (XCD), slot=b>>3; g=slot>>2, qu=slot&3, panel pp=x+8g (64 cols).
// 256 threads, 4 waves = row-quarters (32 rows each), full 64-col width per wave.
__global__ __launch_bounds__(256) void fc_kernel(
    const unsigned short* __restrict__ hseq, const unsigned short* __restrict__ fcwb,
    const float* __restrict__ fcb, const int* __restrict__ nact,
    float* __restrict__ out)
{
  const int b    = blockIdx.x;
  const int x    = b & 7;
  const int slot = b >> 3;
  const int g    = slot >> 2;
  const int qu   = slot & 3;
  const int pp   = x + 8*g;
  if (pp >= 158) return;
  const int v0   = pp * 64;
  const int tid  = threadIdx.x;
  const int lane = tid & 63;
  const int wr   = tid >> 6;          // 0..3 row quarter
  const int fr   = lane & 15;
  const int fk   = (lane >> 4) * 8;

  __shared__ unsigned short Bl[64*520];   // 66.5 KB -> 2 blocks/CU
  for (int idx = tid; idx < 64*64; idx += 256){
    int lr = idx >> 6, kc = (idx & 63) * 8;
    s16x8 v = ld8(fcwb + (size_t)(v0 + lr)*512 + kc);
    *reinterpret_cast<s16x8*>(&Bl[lr*520 + kc]) = v;
  }
  __syncthreads();

  float bb[4];
  for (int j = 0; j < 4; ++j){
    int v = v0 + j*16 + fr;
    bb[j] = (v < 10000) ? fcb[v] : 0.f;
  }

  const int tcnt = (qu == 3) ? 4 : 5;
  for (int ti = 0; ti < tcnt; ++ti){
    const int t   = qu*5 + ti;
    const int n_t = nact[t + 1];
    const unsigned short* A = hseq + (size_t)(t + 2)*65536;

    f32x4 acc[2][4];
    for (int i = 0; i < 2; ++i)
      for (int j = 0; j < 4; ++j)
        acc[i][j] = (f32x4){0.f,0.f,0.f,0.f};

    if (wr*32 < n_t){
      #pragma unroll 4
      for (int k0 = 0; k0 < 512; k0 += 32){
        s16x8 a[2], bf[4];
        for (int i = 0; i < 2; ++i)
          a[i] = ld8(A + (size_t)(wr*32 + i*16 + fr)*512 + k0 + fk);
        for (int j = 0; j < 4; ++j)
          bf[j] = *reinterpret_cast<const s16x8*>(&Bl[(j*16 + fr)*520 + k0 + fk]);
        for (int i = 0; i < 2; ++i)
          for (int j = 0; j < 4; ++j)
            acc[i][j] = MFMA16(a[i], bf[j], acc[i][j]);
      }
    }

    const int rr = (lane >> 4) * 4;
    for (int j = 0; j < 4; ++j){
      int v = v0 + j*16 + fr;
      if (v >= 10000) continue;
      for (int i = 0; i < 2; ++i)
        for (int pp2 = 0; pp2 < 4; ++pp2){
          int r = wr*32 + i*16 + rr + pp2;
          out[(size_t)(r*19 + t)*10000 + v] = (r < n_t) ? (acc[i][j][pp2] + bb[j]) : 0.0f;
        }
    }
  }
}

extern "C" void kernel_launch(void* const* d_in, const int* in_sizes, int n_in,
                              void* d_out, int out_size, void* d_ws, size_t ws_size,
                              hipStream_t stream) {
  const float* images   = (const float*)d_in[0];
  const int*   captions = (const int*)  d_in[1];
  const int*   length   = (const int*)  d_in[2];
  const float* emb      = (const float*)d_in[3];
  const float* W_ih     = (const float*)d_in[4];
  const float* W_hh     = (const float*)d_in[5];
  const float* b_ih     = (const float*)d_in[6];
  const float* b_hh     = (const float*)d_in[7];
  const float* fc_w     = (const float*)d_in[8];
  const float* fc_b     = (const float*)d_in[9];
  float* out = (float*)d_out;
  char*  ws  = (char*)d_ws;

  int*            sortp  = (int*)           (ws + 0);
  int*            nactp  = (int*)           (ws + 2048);
  float*          biasp  = (float*)         (ws + 4096);
  unsigned int*   cnt    = (unsigned int*)  (ws + 12288);
  unsigned short* hseq   = (unsigned short*)(ws + 278528);    // 21 slots x 128x512 bf16
  unsigned short* xseq   = (unsigned short*)(ws + 3031040);   // 20 slots
  unsigned short* wihb   = (unsigned short*)(ws + 5652480);
  unsigned short* whhb   = (unsigned short*)(ws + 7749632);
  unsigned short* fcwb   = (unsigned short*)(ws + 9846784);   // 10112x512 bf16
  float*          gx     = (float*)         (ws + 20201472);  // 20x128x2048 f32, ends ~41.2 MB

  k0_sort<<<1, 128, 0, stream>>>(length, captions, out, sortp, nactp, cnt);
  k1_convert<<<4096, 256, 0, stream>>>(images, captions, emb, W_ih, W_hh, b_ih, b_hh,
                                       fc_w, sortp, wihb, whhb, fcwb, biasp, xseq, hseq);
  k2_gx<<<dim3(16, 20), 256, 0, stream>>>(xseq, wihb, biasp, gx);
  lstm_chain<<<64, 512, 0, stream>>>(gx, whhb, hseq, nactp, cnt);
  fc_kernel<<<640, 256, 0, stream>>>(hseq, fcwb, fc_b, nactp, out);
}

// Round 6
// 242.291 us; speedup vs baseline: 2.4431x; 1.1114x over previous
//
#include <hip/hip_runtime.h>

typedef float  f32x4 __attribute__((ext_vector_type(4)));
typedef short  s16x8 __attribute__((ext_vector_type(8)));
typedef unsigned short u16x4 __attribute__((ext_vector_type(4)));

#define MFMA16(a,b,c) __builtin_amdgcn_mfma_f32_16x16x32_bf16(a,b,c,0,0,0)

// sizes: B=128, S=20, T=19, E=H=512, G=2048, V=10000 (padded 10112)
#define PRED_ELEMS 24320000ull

__device__ __forceinline__ unsigned short f2bf(float f){
  unsigned u = __builtin_bit_cast(unsigned, f);
  u += 0x7fffu + ((u >> 16) & 1u);
  return (unsigned short)(u >> 16);
}
__device__ __forceinline__ float sigf(float x){ return 1.0f/(1.0f + __expf(-x)); }
__device__ __forceinline__ float tanh_(float x){
  x = fminf(15.0f, fmaxf(-15.0f, x));
  float e = __expf(2.0f*x);
  return (e - 1.0f) / (e + 1.0f);
}
__device__ __forceinline__ s16x8 ld8(const unsigned short* p){
  return *reinterpret_cast<const s16x8*>(p);
}

// ---------------- K0: stable descending sort by length, tail outputs, cnt init ----------------
__global__ void k0_sort(const int* __restrict__ length, const int* __restrict__ captions,
                        float* __restrict__ out, int* __restrict__ sortp,
                        int* __restrict__ nactp, unsigned int* __restrict__ cnt)
{
  __shared__ int sl[128], sdl[128], ssi[128];
  int tid = threadIdx.x;
  if (tid < 256) cnt[tid] = 0u;       // 4 counters live at cnt[rb*64], rest padding
  if (tid < 128) sl[tid] = length[tid];
  __syncthreads();
  if (tid < 128){
    int l = sl[tid];
    int rank = 0;
    for (int j = 0; j < 128; ++j){
      int lj = sl[j];
      rank += (lj > l) || (lj == l && j < tid);
    }
    sortp[rank] = tid;
    ssi[rank] = tid;   sdl[rank] = l - 1;
  }
  __syncthreads();
  if (tid < 20){
    int c = 0;
    for (int r = 0; r < 128; ++r) c += (sdl[r] >= tid);
    nactp[tid] = c;
  }
  if (tid < 128){
    const size_t P = PRED_ELEMS;
    int si = ssi[tid];
    for (int t = 0; t < 20; ++t) out[P + tid*20 + t] = (float)captions[si*20 + t];
    out[P + 2560 + tid] = (float)sdl[tid];
    out[P + 2688 + tid] = (float)si;
  }
}

// ---------------- K1: bf16 conversion / gather / zero-init (4-elem units) ----------------
__device__ __forceinline__ void cvt4(unsigned short* dst, const float* src, int u){
  f32x4 v = *reinterpret_cast<const f32x4*>(src + (size_t)u*4);
  u16x4 o;
  o[0]=f2bf(v[0]); o[1]=f2bf(v[1]); o[2]=f2bf(v[2]); o[3]=f2bf(v[3]);
  *reinterpret_cast<u16x4*>(dst + (size_t)u*4) = o;
}

__global__ void k1_convert(const float* __restrict__ images, const int* __restrict__ captions,
    const float* __restrict__ emb, const float* __restrict__ wih, const float* __restrict__ whh,
    const float* __restrict__ bih, const float* __restrict__ bhh, const float* __restrict__ fcw,
    const int* __restrict__ sortp,
    unsigned short* __restrict__ wihb, unsigned short* __restrict__ whhb,
    unsigned short* __restrict__ fcwb, float* __restrict__ biasp,
    unsigned short* __restrict__ xseq, unsigned short* __restrict__ hseq)
{
  const int U0 = 262144;      // W_ih  2048*512/4
  const int U1 = 262144;      // W_hh
  const int U2 = 1294336;     // fc_w padded 10112*512/4
  const int U3 = 512;         // bias 2048/4
  const int U4 = 327680;      // xseq 20*128*512/4
  const int U5 = 16384;       // hseq slot 0 (zero h_init) 128*512/4
  const int total = U0+U1+U2+U3+U4+U5;
  for (int i = blockIdx.x*blockDim.x + threadIdx.x; i < total; i += gridDim.x*blockDim.x){
    int j = i;
    if (j < U0){ cvt4(wihb, wih, j); continue; }
    j -= U0;
    if (j < U1){ cvt4(whhb, whh, j); continue; }
    j -= U1;
    if (j < U2){
      int row = j >> 7;               // (j*4)/512
      if (row < 10000) cvt4(fcwb, fcw, j);
      else { u16x4 z = {0,0,0,0}; *reinterpret_cast<u16x4*>(fcwb + (size_t)j*4) = z; }
      continue;
    }
    j -= U2;
    if (j < U3){
      int e0 = j*4;
      for (int e = 0; e < 4; ++e) biasp[e0+e] = bih[e0+e] + bhh[e0+e];
      continue;
    }
    j -= U3;
    if (j < U4){
      int elem = j*4;
      int s = elem >> 16;             // /65536
      int rem = elem & 65535;
      int r = rem >> 9;
      int k = rem & 511;
      const float* src;
      if (s == 0) src = images + (size_t)sortp[r]*512 + k;
      else {
        int cap = captions[sortp[r]*20 + (s-1)];
        src = emb + (size_t)cap*512 + k;
      }
      f32x4 v = *reinterpret_cast<const f32x4*>(src);
      u16x4 o;
      o[0]=f2bf(v[0]); o[1]=f2bf(v[1]); o[2]=f2bf(v[2]); o[3]=f2bf(v[3]);
      *reinterpret_cast<u16x4*>(xseq + (size_t)j*4) = o;
      continue;
    }
    j -= U4;
    { u16x4 z = {0,0,0,0}; *reinterpret_cast<u16x4*>(hseq + (size_t)j*4) = z; }
  }
}

// ---------------- K2: gx[s][r][g] = x_s @ W_ih^T + bias (all 20 steps batched) ----------------
__global__ __launch_bounds__(256) void k2_gx(
    const unsigned short* __restrict__ xseq, const unsigned short* __restrict__ wihb,
    const float* __restrict__ biasp, float* __restrict__ gx)
{
  const int lane = threadIdx.x & 63;
  const int wv   = threadIdx.x >> 6;
  const int wr   = wv >> 1, wc = wv & 1;
  const int fr   = lane & 15;
  const int fk   = (lane >> 4) * 8;
  const int s    = blockIdx.y;
  const int g0   = blockIdx.x * 128;
  const unsigned short* A = xseq + (size_t)s*65536;

  f32x4 acc[4][4];
  for (int i = 0; i < 4; ++i)
    for (int j = 0; j < 4; ++j)
      acc[i][j] = (f32x4){0.f,0.f,0.f,0.f};

  #pragma unroll 4
  for (int k0 = 0; k0 < 512; k0 += 32){
    s16x8 a[4], b[4];
    for (int i = 0; i < 4; ++i)
      a[i] = ld8(A + (wr*64 + i*16 + fr)*512 + k0 + fk);
    for (int j = 0; j < 4; ++j)
      b[j] = ld8(wihb + (size_t)(g0 + wc*64 + j*16 + fr)*512 + k0 + fk);
    for (int i = 0; i < 4; ++i)
      for (int j = 0; j < 4; ++j)
        acc[i][j] = MFMA16(a[i], b[j], acc[i][j]);
  }

  const int rr = (lane >> 4) * 4;
  for (int j = 0; j < 4; ++j){
    int g = g0 + wc*64 + j*16 + fr;
    float bb = biasp[g];
    for (int i = 0; i < 4; ++i)
      for (int p = 0; p < 4; ++p){
        int r = wr*64 + i*16 + rr + p;
        gx[((size_t)s*128 + r)*2048 + g] = acc[i][j][p] + bb;
      }
  }
}

// ---------------- K3: persistent LSTM chain ----------------
// 64 blocks (rb 0..3 x cb 0..15), 512 threads. Block: rows rb*32..+31, h-cols cb*32..+31.
// h published via relaxed agent-scope atomic exchange (executes at coherent point,
// bypasses non-coherent L2s) -> NO acquire/release (no buffer_inv / buffer_wbl2).
// __syncthreads drains vmcnt => swaps acked at IF$ before tid0's counter add.
// Consumers read each hseq slot exactly once (never cached before) => plain vector
// loads fill from the coherent point; no stale-line hazard.
__global__ __launch_bounds__(512) void lstm_chain(
    const float* __restrict__ gx, const unsigned short* __restrict__ whh,
    unsigned short* __restrict__ hseq, const int* __restrict__ nact,
    unsigned int* __restrict__ cnt)
{
  const int tid  = threadIdx.x;
  const int lane = tid & 63;
  const int w    = tid >> 6;
  const int rh   = w >> 2;            // row half (16 rows)
  const int qc   = w & 3;             // gate (local gatecol 32-slice)
  const int fr   = lane & 15;
  const int fk   = (lane >> 4) * 8;
  const int rb   = blockIdx.x >> 4;   // 0..3
  const int cb   = blockIdx.x & 15;   // 0..15
  unsigned int* mycnt = cnt + rb*64;  // 256B apart -> no false sharing between groups

  __shared__ unsigned short Wl[128*520];   // 133 KB
  __shared__ float lg[32][132];            // 16.9 KB

  for (int idx = tid; idx < 128*64; idx += 512){
    int lr = idx >> 6, kc = (idx & 63) * 8;
    int q = lr >> 5, jj = lr & 31;
    s16x8 v = ld8(whh + (size_t)(q*512 + cb*32 + jj)*512 + kc);
    *reinterpret_cast<s16x8*>(&Wl[lr*520 + kc]) = v;
  }
  __syncthreads();

  const int prow = rb*32 + (tid >> 4);
  const int pj   = (tid & 15) * 2;
  const int arow = rb*32 + rh*16 + fr;
  float creg0 = 0.f, creg1 = 0.f;

  for (int s = 0; s < 20; ++s){
    if (rb*32 >= nact[s]) break;
    const unsigned short* hp = hseq + (size_t)s*65536;
    unsigned short*       hc = hseq + (size_t)(s+1)*65536;

    // one burst: 16 independent A-frags + 4 gx float2s
    s16x8 a[16];
    #pragma unroll
    for (int k = 0; k < 16; ++k)
      a[k] = ld8(hp + arow*512 + k*32 + fk);
    const float* gxr = gx + ((size_t)s*128 + prow)*2048 + cb*32 + pj;
    float2 gvi = *reinterpret_cast<const float2*>(gxr);
    float2 gvf = *reinterpret_cast<const float2*>(gxr + 512);
    float2 gvg = *reinterpret_cast<const float2*>(gxr + 1024);
    float2 gvo = *reinterpret_cast<const float2*>(gxr + 1536);

    f32x4 acc0 = (f32x4){0.f,0.f,0.f,0.f};
    f32x4 acc1 = (f32x4){0.f,0.f,0.f,0.f};
    #pragma unroll
    for (int k = 0; k < 16; ++k){
      s16x8 b0 = *reinterpret_cast<const s16x8*>(&Wl[(qc*32      + fr)*520 + k*32 + fk]);
      s16x8 b1 = *reinterpret_cast<const s16x8*>(&Wl[(qc*32 + 16 + fr)*520 + k*32 + fk]);
      acc0 = MFMA16(a[k], b0, acc0);
      acc1 = MFMA16(a[k], b1, acc1);
    }
    const int rr = (lane >> 4) * 4;
    #pragma unroll
    for (int p = 0; p < 4; ++p){
      lg[rh*16 + rr + p][qc*32      + fr] = acc0[p];
      lg[rh*16 + rr + p][qc*32 + 16 + fr] = acc1[p];
    }
    __syncthreads();

    {
      const int lr = tid >> 4;
      float iv0 = lg[lr][pj]      + gvi.x;
      float iv1 = lg[lr][pj + 1]  + gvi.y;
      float fv0 = lg[lr][32 + pj] + gvf.x;
      float fv1 = lg[lr][33 + pj] + gvf.y;
      float gv0 = lg[lr][64 + pj] + gvg.x;
      float gv1 = lg[lr][65 + pj] + gvg.y;
      float ov0 = lg[lr][96 + pj] + gvo.x;
      float ov1 = lg[lr][97 + pj] + gvo.y;
      creg0 = sigf(fv0)*creg0 + sigf(iv0)*tanh_(gv0);
      creg1 = sigf(fv1)*creg1 + sigf(iv1)*tanh_(gv1);
      float h0 = sigf(ov0)*tanh_(creg0);
      float h1 = sigf(ov1)*tanh_(creg1);
      unsigned hword = (unsigned)f2bf(h0) | ((unsigned)f2bf(h1) << 16);
      // coherent publish: atomic swap executes at the device coherent point
      __hip_atomic_exchange(
        reinterpret_cast<unsigned*>(hc + (size_t)prow*512 + cb*32 + pj),
        hword, __ATOMIC_RELAXED, __HIP_MEMORY_SCOPE_AGENT);
    }
    __syncthreads();   // drains vmcnt -> all swaps acked; protects lg

    if (s < 19 && nact[s+1] > rb*32){
      if (tid == 0){
        __hip_atomic_fetch_add(mycnt, 1u, __ATOMIC_RELAXED, __HIP_MEMORY_SCOPE_AGENT);
        unsigned tgt = (unsigned)(s + 1) * 16u;
        long guard = 0;
        while (__hip_atomic_load(mycnt, __ATOMIC_RELAXED, __HIP_MEMORY_SCOPE_AGENT) < tgt
               && ++guard < (1L << 30))
          __builtin_amdgcn_s_sleep(1);
      }
      __syncthreads();
    }
  }
}

// ---------------- K4: batched FC, 64-col fc_w panel in LDS (2 blocks/CU), t-loop ----------------
// 640 blocks: x=b&7 (XCD), slot=b>>3; g=slot>>2, qu=slot&3, panel pp=x+8g (64 cols).
// 256 threads, 4 waves = row-quarters (32 rows each), full 64-col width per wave.
__global__ __launch_bounds__(256) void fc_kernel(
    const unsigned short* __restrict__ hseq, const unsigned short* __restrict__ fcwb,
    const float* __restrict__ fcb, const int* __restrict__ nact,
    float* __restrict__ out)
{
  const int b    = blockIdx.x;
  const int x    = b & 7;
  const int slot = b >> 3;
  const int g    = slot >> 2;
  const int qu   = slot & 3;
  const int pp   = x + 8*g;
  if (pp >= 158) return;
  const int v0   = pp * 64;
  const int tid  = threadIdx.x;
  const int lane = tid & 63;
  const int wr   = tid >> 6;          // 0..3 row quarter
  const int fr   = lane & 15;
  const int fk   = (lane >> 4) * 8;

  __shared__ unsigned short Bl[64*520];   // 66.5 KB -> 2 blocks/CU
  for (int idx = tid; idx < 64*64; idx += 256){
    int lr = idx >> 6, kc = (idx & 63) * 8;
    s16x8 v = ld8(fcwb + (size_t)(v0 + lr)*512 + kc);
    *reinterpret_cast<s16x8*>(&Bl[lr*520 + kc]) = v;
  }
  __syncthreads();

  float bb[4];
  for (int j = 0; j < 4; ++j){
    int v = v0 + j*16 + fr;
    bb[j] = (v < 10000) ? fcb[v] : 0.f;
  }

  const int tcnt = (qu == 3) ? 4 : 5;
  for (int ti = 0; ti < tcnt; ++ti){
    const int t   = qu*5 + ti;
    const int n_t = nact[t + 1];
    const unsigned short* A = hseq + (size_t)(t + 2)*65536;

    f32x4 acc[2][4];
    for (int i = 0; i < 2; ++i)
      for (int j = 0; j < 4; ++j)
        acc[i][j] = (f32x4){0.f,0.f,0.f,0.f};

    if (wr*32 < n_t){
      #pragma unroll 4
      for (int k0 = 0; k0 < 512; k0 += 32){
        s16x8 a[2], bf[4];
        for (int i = 0; i < 2; ++i)
          a[i] = ld8(A + (size_t)(wr*32 + i*16 + fr)*512 + k0 + fk);
        for (int j = 0; j < 4; ++j)
          bf[j] = *reinterpret_cast<const s16x8*>(&Bl[(j*16 + fr)*520 + k0 + fk]);
        for (int i = 0; i < 2; ++i)
          for (int j = 0; j < 4; ++j)
            acc[i][j] = MFMA16(a[i], bf[j], acc[i][j]);
      }
    }

    const int rr = (lane >> 4) * 4;
    for (int j = 0; j < 4; ++j){
      int v = v0 + j*16 + fr;
      if (v >= 10000) continue;
      for (int i = 0; i < 2; ++i)
        for (int pp2 = 0; pp2 < 4; ++pp2){
          int r = wr*32 + i*16 + rr + pp2;
          out[(size_t)(r*19 + t)*10000 + v] = (r < n_t) ? (acc[i][j][pp2] + bb[j]) : 0.0f;
        }
    }
  }
}

extern "C" void kernel_launch(void* const* d_in, const int* in_sizes, int n_in,
                              void* d_out, int out_size, void* d_ws, size_t ws_size,
                              hipStream_t stream) {
  const float* images   = (const float*)d_in[0];
  const int*   captions = (const int*)  d_in[1];
  const int*   length   = (const int*)  d_in[2];
  const float* emb      = (const float*)d_in[3];
  const float* W_ih     = (const float*)d_in[4];
  const float* W_hh     = (const float*)d_in[5];
  const float* b_ih     = (const float*)d_in[6];
  const float* b_hh     = (const float*)d_in[7];
  const float* fc_w     = (const float*)d_in[8];
  const float* fc_b     = (const float*)d_in[9];
  float* out = (float*)d_out;
  char*  ws  = (char*)d_ws;

  int*            sortp  = (int*)           (ws + 0);
  int*            nactp  = (int*)           (ws + 2048);
  float*          biasp  = (float*)         (ws + 4096);
  unsigned int*   cnt    = (unsigned int*)  (ws + 12288);     // 1 KB region
  unsigned short* hseq   = (unsigned short*)(ws + 278528);    // 21 slots x 128x512 bf16
  unsigned short* xseq   = (unsigned short*)(ws + 3031040);   // 20 slots
  unsigned short* wihb   = (unsigned short*)(ws + 5652480);
  unsigned short* whhb   = (unsigned short*)(ws + 7749632);
  unsigned short* fcwb   = (unsigned short*)(ws + 9846784);   // 10112x512 bf16
  float*          gx     = (float*)         (ws + 20201472);  // 20x128x2048 f32, ends ~41.2 MB

  k0_sort<<<1, 128, 0, stream>>>(length, captions, out, sortp, nactp, cnt);
  k1_convert<<<4096, 256, 0, stream>>>(images, captions, emb, W_ih, W_hh, b_ih, b_hh,
                                       fc_w, sortp, wihb, whhb, fcwb, biasp, xseq, hseq);
  k2_gx<<<dim3(16, 20), 256, 0, stream>>>(xseq, wihb, biasp, gx);
  lstm_chain<<<64, 512, 0, stream>>>(gx, whhb, hseq, nactp, cnt);
  fc_kernel<<<640, 256, 0, stream>>>(hseq, fcwb, fc_b, nactp, out);
}

// Round 7
// 180.935 us; speedup vs baseline: 3.2715x; 1.3391x over previous
//
#include <hip/hip_runtime.h>

typedef float  f32x4 __attribute__((ext_vector_type(4)));
typedef short  s16x8 __attribute__((ext_vector_type(8)));
typedef unsigned short u16x4 __attribute__((ext_vector_type(4)));

#define MFMA16(a,b,c) __builtin_amdgcn_mfma_f32_16x16x32_bf16(a,b,c,0,0,0)

// sizes: B=128, S=20, T=19, E=H=512, G=2048, V=10000 (padded 10112)
#define PRED_ELEMS 24320000ull

__device__ __forceinline__ unsigned short f2bf(float f){
  unsigned u = __builtin_bit_cast(unsigned, f);
  u += 0x7fffu + ((u >> 16) & 1u);
  return (unsigned short)(u >> 16);
}
__device__ __forceinline__ float sigf(float x){ return 1.0f/(1.0f + __expf(-x)); }
__device__ __forceinline__ float tanh_(float x){
  x = fminf(15.0f, fmaxf(-15.0f, x));
  float e = __expf(2.0f*x);
  return (e - 1.0f) / (e + 1.0f);
}
__device__ __forceinline__ s16x8 ld8(const unsigned short* p){
  return *reinterpret_cast<const s16x8*>(p);
}

// ---------------- K0: stable descending sort by length, tail outputs, counter init ----------------
__global__ void k0_sort(const int* __restrict__ length, const int* __restrict__ captions,
                        float* __restrict__ out, int* __restrict__ sortp,
                        int* __restrict__ nactp, unsigned int* __restrict__ cnt4k)
{
  __shared__ int sl[128], sdl[128], ssi[128];
  int tid = threadIdx.x;
  for (int k = tid; k < 1024; k += 128) cnt4k[k] = 0u;   // claim + barrier counters (4 KB)
  if (tid < 128) sl[tid] = length[tid];
  __syncthreads();
  if (tid < 128){
    int l = sl[tid];
    int rank = 0;
    for (int j = 0; j < 128; ++j){
      int lj = sl[j];
      rank += (lj > l) || (lj == l && j < tid);
    }
    sortp[rank] = tid;
    ssi[rank] = tid;   sdl[rank] = l - 1;
  }
  __syncthreads();
  if (tid < 20){
    int c = 0;
    for (int r = 0; r < 128; ++r) c += (sdl[r] >= tid);
    nactp[tid] = c;
  }
  if (tid < 128){
    const size_t P = PRED_ELEMS;
    int si = ssi[tid];
    for (int t = 0; t < 20; ++t) out[P + tid*20 + t] = (float)captions[si*20 + t];
    out[P + 2560 + tid] = (float)sdl[tid];
    out[P + 2688 + tid] = (float)si;
  }
}

// ---------------- K1: bf16 conversion / gather / zero-init (4-elem units) ----------------
__device__ __forceinline__ void cvt4(unsigned short* dst, const float* src, int u){
  f32x4 v = *reinterpret_cast<const f32x4*>(src + (size_t)u*4);
  u16x4 o;
  o[0]=f2bf(v[0]); o[1]=f2bf(v[1]); o[2]=f2bf(v[2]); o[3]=f2bf(v[3]);
  *reinterpret_cast<u16x4*>(dst + (size_t)u*4) = o;
}

__global__ void k1_convert(const float* __restrict__ images, const int* __restrict__ captions,
    const float* __restrict__ emb, const float* __restrict__ wih, const float* __restrict__ whh,
    const float* __restrict__ bih, const float* __restrict__ bhh, const float* __restrict__ fcw,
    const int* __restrict__ sortp,
    unsigned short* __restrict__ wihb, unsigned short* __restrict__ whhb,
    unsigned short* __restrict__ fcwb, float* __restrict__ biasp,
    unsigned short* __restrict__ xseq, unsigned short* __restrict__ hseq,
    unsigned short* __restrict__ hloc)
{
  const int U0 = 262144;      // W_ih  2048*512/4
  const int U1 = 262144;      // W_hh
  const int U2 = 1294336;     // fc_w padded 10112*512/4
  const int U3 = 512;         // bias 2048/4
  const int U4 = 327680;      // xseq 20*128*512/4
  const int U5 = 16384;       // hseq canonical slot 0 (zero h_init)
  const int U6 = 16384;       // hloc slot 0 per XCD (8 x 16 x 512)
  const int total = U0+U1+U2+U3+U4+U5+U6;
  for (int i = blockIdx.x*blockDim.x + threadIdx.x; i < total; i += gridDim.x*blockDim.x){
    int j = i;
    if (j < U0){ cvt4(wihb, wih, j); continue; }
    j -= U0;
    if (j < U1){ cvt4(whhb, whh, j); continue; }
    j -= U1;
    if (j < U2){
      int row = j >> 7;               // (j*4)/512
      if (row < 10000) cvt4(fcwb, fcw, j);
      else { u16x4 z = {0,0,0,0}; *reinterpret_cast<u16x4*>(fcwb + (size_t)j*4) = z; }
      continue;
    }
    j -= U2;
    if (j < U3){
      int e0 = j*4;
      for (int e = 0; e < 4; ++e) biasp[e0+e] = bih[e0+e] + bhh[e0+e];
      continue;
    }
    j -= U3;
    if (j < U4){
      int elem = j*4;
      int s = elem >> 16;             // /65536
      int rem = elem & 65535;
      int r = rem >> 9;
      int k = rem & 511;
      const float* src;
      if (s == 0) src = images + (size_t)sortp[r]*512 + k;
      else {
        int cap = captions[sortp[r]*20 + (s-1)];
        src = emb + (size_t)cap*512 + k;
      }
      f32x4 v = *reinterpret_cast<const f32x4*>(src);
      u16x4 o;
      o[0]=f2bf(v[0]); o[1]=f2bf(v[1]); o[2]=f2bf(v[2]); o[3]=f2bf(v[3]);
      *reinterpret_cast<u16x4*>(xseq + (size_t)j*4) = o;
      continue;
    }
    j -= U4;
    if (j < U5){ u16x4 z = {0,0,0,0}; *reinterpret_cast<u16x4*>(hseq + (size_t)j*4) = z; continue; }
    j -= U5;
    { // hloc slot 0 per XCD: hloc[x][0][16][512]
      int e0 = j*4;
      int x = e0 >> 13;               // /8192 (16*512)
      int rem = e0 & 8191;
      u16x4 z = {0,0,0,0};
      *reinterpret_cast<u16x4*>(hloc + (size_t)x*172032 + rem) = z;  // 21*16*512 per XCD
    }
  }
}

// ---------------- K2: gx[s][r][g] = x_s @ W_ih^T + bias (all 20 steps batched) ----------------
__global__ __launch_bounds__(256) void k2_gx(
    const unsigned short* __restrict__ xseq, const unsigned short* __restrict__ wihb,
    const float* __restrict__ biasp, float* __restrict__ gx)
{
  const int lane = threadIdx.x & 63;
  const int wv   = threadIdx.x >> 6;
  const int wr   = wv >> 1, wc = wv & 1;
  const int fr   = lane & 15;
  const int fk   = (lane >> 4) * 8;
  const int s    = blockIdx.y;
  const int g0   = blockIdx.x * 128;
  const unsigned short* A = xseq + (size_t)s*65536;

  f32x4 acc[4][4];
  for (int i = 0; i < 4; ++i)
    for (int j = 0; j < 4; ++j)
      acc[i][j] = (f32x4){0.f,0.f,0.f,0.f};

  #pragma unroll 4
  for (int k0 = 0; k0 < 512; k0 += 32){
    s16x8 a[4], b[4];
    for (int i = 0; i < 4; ++i)
      a[i] = ld8(A + (wr*64 + i*16 + fr)*512 + k0 + fk);
    for (int j = 0; j < 4; ++j)
      b[j] = ld8(wihb + (size_t)(g0 + wc*64 + j*16 + fr)*512 + k0 + fk);
    for (int i = 0; i < 4; ++i)
      for (int j = 0; j < 4; ++j)
        acc[i][j] = MFMA16(a[i], b[j], acc[i][j]);
  }

  const int rr = (lane >> 4) * 4;
  for (int j = 0; j < 4; ++j){
    int g = g0 + wc*64 + j*16 + fr;
    float bb = biasp[g];
    for (int i = 0; i < 4; ++i)
      for (int p = 0; p < 4; ++p){
        int r = wr*64 + i*16 + rr + p;
        gx[((size_t)s*128 + r)*2048 + g] = acc[i][j][p] + bb;
      }
  }
}

// ---------------- K3: XCD-local persistent LSTM chain ----------------
// 256 blocks x 256 threads, ~84.5 KB LDS -> exactly 1 block/CU -> exactly 32 blocks
// per XCD (capacity-forced). Block reads its physical XCD (HW_REG_XCC_ID, hwreg 20),
// claims slot w=0..31 on a per-XCD counter. XCD x owns rows [16x,16x+16); worker w
// owns h-cols [16w,16w+16) (W_hh slice 64x512 in LDS). h exchanged via plain
// stores/loads in the XCD-local L2 copy (write-through L1, no write-allocate; each
// slot line read once -> L1 always cold -> L2-fresh). Barrier: per-XCD counter,
// agent-scope relaxed. h also mirrored to canonical hseq for the later FC.
__global__ __launch_bounds__(256) void lstm_chain(
    const float* __restrict__ gx, const unsigned short* __restrict__ whh,
    unsigned short* __restrict__ hseq, unsigned short* __restrict__ hloc,
    const int* __restrict__ nact, unsigned int* __restrict__ claimc,
    unsigned int* __restrict__ barc)
{
  const int tid = threadIdx.x;
  __shared__ int s_xw;
  __shared__ unsigned short Wl[64*524];     // 67.1 KB (stride 524: 4-way max on b128 reads)
  __shared__ float pg[4][4][16][17];        // 17.4 KB partial gates (kk, q, row, col)

  if (tid == 0){
    unsigned xcc;
    asm volatile("s_getreg_b32 %0, hwreg(20, 0, 4)" : "=s"(xcc));  // HW_REG_XCC_ID
    int x = (int)(xcc & 7u);
    unsigned slot = __hip_atomic_fetch_add(claimc + x*64, 1u,
                      __ATOMIC_RELAXED, __HIP_MEMORY_SCOPE_AGENT);
    s_xw = (x << 8) | (int)(slot & 255u);
  }
  __syncthreads();
  const int x = s_xw >> 8;
  const int w = s_xw & 255;
  if (w >= 32) return;                       // can't happen if capacity math holds
  const int R0 = x*16;
  const int C0 = w*16;
  unsigned int* mybar = barc + x*64;

  const int lane = tid & 63;
  const int kk   = tid >> 6;                 // wave = k-quarter (128 of 512)
  const int fr   = lane & 15;
  const int fkq  = (lane >> 4) * 8;

  // preload W_hh slice: local row lr=q*16+jj <-> W_hh row q*512 + C0 + jj
  for (int idx = tid; idx < 64*64; idx += 256){
    int lr = idx >> 6, kc = (idx & 63)*8;
    int q = lr >> 4, jj = lr & 15;
    s16x8 v = ld8(whh + (size_t)(q*512 + C0 + jj)*512 + kc);
    *reinterpret_cast<s16x8*>(&Wl[lr*524 + kc]) = v;
  }

  unsigned short* hl = hloc + (size_t)x*172032;   // [21][16][512]
  const int prow = tid >> 4;                 // pointwise row 0..15
  const int pcol = tid & 15;                 // pointwise col 0..15
  float creg = 0.f;
  __syncthreads();

  for (int s = 0; s < 20; ++s){
    if (R0 >= nact[s]) break;
    const unsigned short* hp = hl + (size_t)s*8192;

    // A fragments (16 rows x this wave's k-quarter) + gx for pointwise
    s16x8 a[4];
    #pragma unroll
    for (int i = 0; i < 4; ++i)
      a[i] = ld8(hp + fr*512 + kk*128 + i*32 + fkq);
    const float* gxr = gx + ((size_t)s*128 + R0 + prow)*2048 + C0 + pcol;
    float gvi = gxr[0], gvf = gxr[512], gvg = gxr[1024], gvo = gxr[1536];

    // partial gates: this wave's k-quarter, all 4 gates
    #pragma unroll
    for (int q = 0; q < 4; ++q){
      f32x4 acc = (f32x4){0.f,0.f,0.f,0.f};
      #pragma unroll
      for (int i = 0; i < 4; ++i){
        s16x8 b = *reinterpret_cast<const s16x8*>(&Wl[(q*16 + fr)*524 + kk*128 + i*32 + fkq]);
        acc = MFMA16(a[i], b, acc);
      }
      const int rr = (lane >> 4) * 4;
      #pragma unroll
      for (int p = 0; p < 4; ++p)
        pg[kk][q][rr + p][fr] = acc[p];
    }
    __syncthreads();

    // pointwise: sum 4 k-partials per gate, cell update, publish h
    {
      float iv = pg[0][0][prow][pcol] + pg[1][0][prow][pcol]
               + pg[2][0][prow][pcol] + pg[3][0][prow][pcol] + gvi;
      float fv = pg[0][1][prow][pcol] + pg[1][1][prow][pcol]
               + pg[2][1][prow][pcol] + pg[3][1][prow][pcol] + gvf;
      float gv = pg[0][2][prow][pcol] + pg[1][2][prow][pcol]
               + pg[2][2][prow][pcol] + pg[3][2][prow][pcol] + gvg;
      float ov = pg[0][3][prow][pcol] + pg[1][3][prow][pcol]
               + pg[2][3][prow][pcol] + pg[3][3][prow][pcol] + gvo;
      creg = sigf(fv)*creg + sigf(iv)*tanh_(gv);
      float h = sigf(ov)*tanh_(creg);
      unsigned short hb = f2bf(h);
      hl[(size_t)(s+1)*8192 + prow*512 + C0 + pcol] = hb;                    // XCD-local
      hseq[(size_t)(s+1)*65536 + (R0 + prow)*512 + C0 + pcol] = hb;          // canonical
    }
    __syncthreads();   // drains vmcnt: stores are in this XCD's L2; protects pg

    if (s < 19 && nact[s+1] > R0){
      if (tid == 0){
        __hip_atomic_fetch_add(mybar, 1u, __ATOMIC_RELAXED, __HIP_MEMORY_SCOPE_AGENT);
        unsigned tgt = (unsigned)(s + 1) * 32u;
        long guard = 0;
        while (__hip_atomic_load(mybar, __ATOMIC_RELAXED, __HIP_MEMORY_SCOPE_AGENT) < tgt
               && ++guard < (1L << 21))
          __builtin_amdgcn_s_sleep(2);
      }
      __syncthreads();
    }
  }
}

// ---------------- K4: batched FC, 64-col fc_w panel in LDS (2 blocks/CU), t-loop ----------------
__global__ __launch_bounds__(256) void fc_kernel(
    const unsigned short* __restrict__ hseq, const unsigned short* __restrict__ fcwb,
    const float* __restrict__ fcb, const int* __restrict__ nact,
    float* __restrict__ out)
{
  const int b    = blockIdx.x;
  const int x    = b & 7;
  const int slot = b >> 3;
  const int g    = slot >> 2;
  const int qu   = slot & 3;
  const int pp   = x + 8*g;
  if (pp >= 158) return;
  const int v0   = pp * 64;
  const int tid  = threadIdx.x;
  const int lane = tid & 63;
  const int wr   = tid >> 6;          // 0..3 row quarter
  const int fr   = lane & 15;
  const int fk   = (lane >> 4) * 8;

  __shared__ unsigned short Bl[64*520];   // 66.5 KB -> 2 blocks/CU
  for (int idx = tid; idx < 64*64; idx += 256){
    int lr = idx >> 6, kc = (idx & 63) * 8;
    s16x8 v = ld8(fcwb + (size_t)(v0 + lr)*512 + kc);
    *reinterpret_cast<s16x8*>(&Bl[lr*520 + kc]) = v;
  }
  __syncthreads();

  float bb[4];
  for (int j = 0; j < 4; ++j){
    int v = v0 + j*16 + fr;
    bb[j] = (v < 10000) ? fcb[v] : 0.f;
  }

  const int tcnt = (qu == 3) ? 4 : 5;
  for (int ti = 0; ti < tcnt; ++ti){
    const int t   = qu*5 + ti;
    const int n_t = nact[t + 1];
    const unsigned short* A = hseq + (size_t)(t + 2)*65536;

    f32x4 acc[2][4];
    for (int i = 0; i < 2; ++i)
      for (int j = 0; j < 4; ++j)
        acc[i][j] = (f32x4){0.f,0.f,0.f,0.f};

    if (wr*32 < n_t){
      #pragma unroll 4
      for (int k0 = 0; k0 < 512; k0 += 32){
        s16x8 a[2], bf[4];
        for (int i = 0; i < 2; ++i)
          a[i] = ld8(A + (size_t)(wr*32 + i*16 + fr)*512 + k0 + fk);
        for (int j = 0; j < 4; ++j)
          bf[j] = *reinterpret_cast<const s16x8*>(&Bl[(j*16 + fr)*520 + k0 + fk]);
        for (int i = 0; i < 2; ++i)
          for (int j = 0; j < 4; ++j)
            acc[i][j] = MFMA16(a[i], bf[j], acc[i][j]);
      }
    }

    const int rr = (lane >> 4) * 4;
    for (int j = 0; j < 4; ++j){
      int v = v0 + j*16 + fr;
      if (v >= 10000) continue;
      for (int i = 0; i < 2; ++i)
        for (int pp2 = 0; pp2 < 4; ++pp2){
          int r = wr*32 + i*16 + rr + pp2;
          out[(size_t)(r*19 + t)*10000 + v] = (r < n_t) ? (acc[i][j][pp2] + bb[j]) : 0.0f;
        }
    }
  }
}

extern "C" void kernel_launch(void* const* d_in, const int* in_sizes, int n_in,
                              void* d_out, int out_size, void* d_ws, size_t ws_size,
                              hipStream_t stream) {
  const float* images   = (const float*)d_in[0];
  const int*   captions = (const int*)  d_in[1];
  const int*   length   = (const int*)  d_in[2];
  const float* emb      = (const float*)d_in[3];
  const float* W_ih     = (const float*)d_in[4];
  const float* W_hh     = (const float*)d_in[5];
  const float* b_ih     = (const float*)d_in[6];
  const float* b_hh     = (const float*)d_in[7];
  const float* fc_w     = (const float*)d_in[8];
  const float* fc_b     = (const float*)d_in[9];
  float* out = (float*)d_out;
  char*  ws  = (char*)d_ws;

  int*            sortp  = (int*)           (ws + 0);
  int*            nactp  = (int*)           (ws + 2048);
  float*          biasp  = (float*)         (ws + 4096);
  unsigned int*   cnt4k  = (unsigned int*)  (ws + 12288);     // claim[8] + bar[8], 256B strides
  unsigned int*   claimc = cnt4k;                              // claimc + x*64
  unsigned int*   barc   = cnt4k + 512;                        // barc + x*64
  unsigned short* hloc   = (unsigned short*)(ws + 16384);      // 8 x [21][16][512] bf16
  unsigned short* hseq   = (unsigned short*)(ws + 2768896);    // canonical 21 x 128 x 512 bf16
  unsigned short* xseq   = (unsigned short*)(ws + 5521408);    // 20 slots
  unsigned short* wihb   = (unsigned short*)(ws + 8142848);
  unsigned short* whhb   = (unsigned short*)(ws + 10240000);
  unsigned short* fcwb   = (unsigned short*)(ws + 12337152);   // 10112x512 bf16
  float*          gx     = (float*)         (ws + 22691840);   // 20x128x2048 f32, ends ~43.7 MB

  k0_sort<<<1, 128, 0, stream>>>(length, captions, out, sortp, nactp, cnt4k);
  k1_convert<<<4096, 256, 0, stream>>>(images, captions, emb, W_ih, W_hh, b_ih, b_hh,
                                       fc_w, sortp, wihb, whhb, fcwb, biasp, xseq, hseq, hloc);
  k2_gx<<<dim3(16, 20), 256, 0, stream>>>(xseq, wihb, biasp, gx);
  lstm_chain<<<256, 256, 0, stream>>>(gx, whhb, hseq, hloc, nactp, claimc, barc);
  fc_kernel<<<640, 256, 0, stream>>>(hseq, fcwb, fc_b, nactp, out);
}